// Round 13
// baseline (187.821 us; speedup 1.0000x reference)
//
#include <hip/hip_runtime.h>

typedef short short8 __attribute__((ext_vector_type(8)));
typedef float f32x4 __attribute__((ext_vector_type(4)));

#define T_ 12
#define B_ 256
#define N_ 35
#define M_ 29
#define H_ 64
#define R_ 7

// ---- ws (shorts) layout: packed bf16 MFMA B-fragments ----
// W6F   @0     : 6 mats x [nt4][ks2][64][8]   = 24576 shorts
// WQKF  @24576 : 2 mats x [nt4][64][8]        = 4096
// WRELF @28672 : 7 r    x [nt4][64][8]        = 14336

// ---- msg_kernel static LDS (bytes), phase-overlaid ----
#define XA_OFF   0
#define XB_OFF   3072
#define Q_OFF    7168
#define K_OFF    16384
#define E_OFF    25344
#define INV_OFF  46064
#define S2_OFF   7168
#define AN_OFF   12208
#define AXB_OFF  20608
#define SMEM_A   47232

__device__ __forceinline__ unsigned short f2bf(float f) {
    unsigned int u = __float_as_uint(f);
    u += 0x7fffu + ((u >> 16) & 1u);
    return (unsigned short)(u >> 16);
}
__device__ __forceinline__ float bf2f(unsigned short s) {
    return __uint_as_float(((unsigned int)s) << 16);
}

// ---------------- pack: weights -> bf16 fragment order in ws ----------------
__global__ void pack_kernel(const float* __restrict__ Wq, const float* __restrict__ Wk,
                            const float* __restrict__ coef, const float* __restrict__ V,
                            const float* __restrict__ Uz, const float* __restrict__ Wz,
                            const float* __restrict__ Ur, const float* __restrict__ Wrg,
                            const float* __restrict__ Uh, const float* __restrict__ Wh,
                            unsigned short* __restrict__ ws) {
    int idx = blockIdx.x * 256 + threadIdx.x;   // grid covers exactly 43008
    if (idx < 24576) {                          // W6
        int mat = idx >> 12, rem = idx & 4095;
        int i = rem & 7, l = (rem >> 3) & 63, ks = (rem >> 9) & 1, nt = rem >> 10;
        int j = ks * 32 + ((l >> 4) << 3) + i, c = nt * 16 + (l & 15);
        const float* W = (mat == 0) ? Uz : (mat == 1) ? Wz : (mat == 2) ? Ur
                       : (mat == 3) ? Wrg : (mat == 4) ? Uh : Wh;
        ws[idx] = f2bf(W[j * 64 + c]);
    } else if (idx < 28672) {                   // WQK
        int rem = idx - 24576;
        int mq = rem >> 11; rem &= 2047;
        int i = rem & 7, l = (rem >> 3) & 63, nt = rem >> 9;
        int j = ((l >> 4) << 3) + i, c = nt * 16 + (l & 15);
        const float* W = mq ? Wk : Wq;
        ws[idx] = (j < M_) ? f2bf(W[j * 64 + c]) : (unsigned short)0;
    } else {                                    // WREL
        int rem = idx - 28672;
        int r = rem >> 11; rem &= 2047;
        int i = rem & 7, l = (rem >> 3) & 63, nt = rem >> 9;
        int j = ((l >> 4) << 3) + i, c = nt * 16 + (l & 15);
        unsigned short v = 0;
        if (j < M_) {
            float a = 0.f;
#pragma unroll
            for (int bb = 0; bb < 3; ++bb) a += coef[r * 3 + bb] * V[(bb * M_ + j) * 64 + c];
            v = f2bf(a);
        }
        ws[idx] = v;
    }
}

// --------- msg: one block per (t,b); msg bf16 -> upper half of out[t] rows ---------
__launch_bounds__(512, 4)
__global__ void msg_kernel(const float* __restrict__ x,
                           const float* __restrict__ As, const float* __restrict__ Af,
                           const float* __restrict__ At,
                           const unsigned short* __restrict__ wsF,
                           float* __restrict__ out) {
    __shared__ __align__(16) char smem[SMEM_A];
    const int blk = blockIdx.x;
    const int t = blk >> 8, b = blk & 255;
    const int tid = threadIdx.x, wv = tid >> 6, ln = tid & 63;
    const unsigned short* WQKF  = wsF + 24576;
    const unsigned short* WRELF = wsF + 28672;
    const float* __restrict__ xt = x + ((size_t)t * B_ + b) * (N_ * M_);

    for (int e = tid; e < 1536; e += 512) {
        int mt = e >> 9, l = (e >> 3) & 63, i = e & 7;
        int row = mt * 16 + (l & 15), k = ((l >> 4) << 3) + i;
        float v = (row < N_ && k < M_) ? xt[row * M_ + k] : 0.f;
        *(unsigned short*)(smem + XA_OFF + e * 2) = f2bf(v);
    }
    for (int e = tid; e < 2048; e += 512) {
        int g = e >> 9, l = (e >> 3) & 63, i = e & 7;
        int ks = g >> 1, nt = g & 1;
        int k = ks * 32 + ((l >> 4) << 3) + i, c = nt * 16 + (l & 15);
        float v = (k < N_ && c < M_) ? xt[k * M_ + c] : 0.f;
        *(unsigned short*)(smem + XB_OFF + e * 2) = f2bf(v);
    }
    __syncthreads();

    // p2: q = x@Wq (swz fp32), k = x@Wk (linear fp32)
    for (int tile = wv; tile < 24; tile += 8) {
        int qk = (tile >= 12) ? 1 : 0;
        int tt = tile - 12 * qk;
        int mt = tt >> 2, nt = tt & 3;
        short8 a  = *(const short8*)(smem + XA_OFF + (mt * 64 + ln) * 16);
        short8 bb = *(const short8*)(WQKF + (qk * 4 + nt) * 512 + ln * 8);
        f32x4 d = {0.f, 0.f, 0.f, 0.f};
        d = __builtin_amdgcn_mfma_f32_16x16x32_bf16(a, bb, d, 0, 0, 0);
        int col = nt * 16 + (ln & 15);
#pragma unroll
        for (int j = 0; j < 4; ++j) {
            int row = mt * 16 + ((ln >> 4) << 2) + j;
            if (row < N_) {
                if (qk) *(float*)(smem + K_OFF + (row * 64 + col) * 4) = d[j];
                else {
                    int ad = (Q_OFF + row * 256 + col * 4) ^ ((row & 7) << 4);
                    *(float*)(smem + ad) = d[j];
                }
            }
        }
    }
    __syncthreads();

    // p3: wave = head; lane = n-row; single-pass exp (no max, no atomics), dual-sum dot
    {
        const int hd = wv, n = ln;
        const int nn = (n < N_) ? n : 34;
        const int qb = Q_OFF + nn * 256 + hd * 32;
        const int swzq = (nn & 7) << 4;
        f32x4 q0 = *(const f32x4*)(smem + (qb ^ swzq));
        f32x4 q1 = *(const f32x4*)(smem + ((qb + 16) ^ swzq));
        float sum = 0.f;
        unsigned short* Erow = (unsigned short*)(smem + E_OFF) + (hd * 35 + nn) * 37;
#pragma unroll
        for (int m = 0; m < N_; ++m) {
            f32x4 k0 = *(const f32x4*)(smem + K_OFF + (m * 64 + hd * 8) * 4);
            f32x4 k1 = *(const f32x4*)(smem + K_OFF + (m * 64 + hd * 8 + 4) * 4);
            float accA = q0[0]*k0[0] + q0[1]*k0[1] + q0[2]*k0[2] + q0[3]*k0[3];
            float accB = q1[0]*k1[0] + q1[1]*k1[1] + q1[2]*k1[2] + q1[3]*k1[3];
            float e = __expf((accA + accB) * 0.3535533905932738f);
            sum += e;
            if (n < N_) Erow[m] = f2bf(e);
        }
        if (n < N_) *((float*)(smem + INV_OFF) + hd * 35 + n) = __builtin_amdgcn_rcpf(sum);
    }
    __syncthreads();

    // p3.5: S[n][m] = sum_h E*inv
    {
        const unsigned short* E = (const unsigned short*)(smem + E_OFF);
        const float* IV = (const float*)(smem + INV_OFF);
        float* S = (float*)(smem + S2_OFF);
        for (int e = tid; e < 1225; e += 512) {
            int n = e / 35, m = e - n * 35;
            float sA = 0.f, sB = 0.f;
#pragma unroll
            for (int h = 0; h < 4; ++h) {
                sA += bf2f(E[(h * 35 + n) * 37 + m]) * IV[h * 35 + n];
                sB += bf2f(E[((h + 4) * 35 + n) * 37 + m]) * IV[(h + 4) * 35 + n];
            }
            S[n * 36 + m] = sA + sB;
        }
    }
    __syncthreads();

    // p4: An = l2norm(A * S)
    if (tid < 420) {
        int g = tid >> 2, sub = tid & 3;
        int mat = g / N_, j = g - N_ * mat;
        const float* __restrict__ A = (mat == 0) ? As : ((mat == 1) ? Af : At);
        float vals[9]; float ss = 0.f;
#pragma unroll
        for (int i = 0; i < 9; ++i) {
            int n = sub + 4 * i;
            float vv = 0.f;
            if (n < N_) vv = A[n * N_ + j] * *((const float*)(smem + S2_OFF) + n * 36 + j);
            vals[i] = vv; ss += vv * vv;
        }
        ss += __shfl_xor(ss, 1);
        ss += __shfl_xor(ss, 2);
        float inv = 1.f / fmaxf(sqrtf(ss), 1e-12f);
#pragma unroll
        for (int i = 0; i < 9; ++i) {
            int n = sub + 4 * i;
            if (n < N_)
                *(unsigned short*)(smem + AN_OFF + ((mat * 35 + n) * 40 + j) * 2) = f2bf(vals[i] * inv);
        }
    }
    for (int e = tid; e < 525; e += 512) {
        int mat = e / 175, rem = e - mat * 175;
        int n = rem / 5, pc = rem - n * 5;
        *(unsigned short*)(smem + AN_OFF + ((mat * 35 + n) * 40 + 35 + pc) * 2) = 0;
    }
    __syncthreads();

    // p5a: 3 base products An_i @ x
    for (int g = wv; g < 9; g += 8) {
        int base = g / 3, mt = g - 3 * base;
        const int row = mt * 16 + (ln & 15);
        const int rowc = (row < N_) ? row : 34;
        const short8 z8 = {0, 0, 0, 0, 0, 0, 0, 0};
        short8 aF[2];
#pragma unroll
        for (int ks = 0; ks < 2; ++ks) {
            int k0 = ks * 32 + ((ln >> 4) << 3);
            int k0c = (k0 <= 32) ? k0 : 32;
            short8 v = *(const short8*)(smem + AN_OFF + ((base * 35 + rowc) * 40 + k0c) * 2);
            aF[ks] = (row < N_ && k0 <= 32) ? v : z8;
        }
        float* axb = (float*)(smem + AXB_OFF) + base * (35 * 44);
#pragma unroll
        for (int nt = 0; nt < 2; ++nt) {
            f32x4 d = {0.f, 0.f, 0.f, 0.f};
#pragma unroll
            for (int ks = 0; ks < 2; ++ks) {
                short8 bb = *(const short8*)(smem + XB_OFF + ((ks * 2 + nt) * 64 + ln) * 16);
                d = __builtin_amdgcn_mfma_f32_16x16x32_bf16(aF[ks], bb, d, 0, 0, 0);
            }
            int col = nt * 16 + (ln & 15);
#pragma unroll
            for (int j = 0; j < 4; ++j) {
                int rw = mt * 16 + ((ln >> 4) << 2) + j;
                if (rw < N_) axb[rw * 44 + col] = d[j];
            }
        }
    }
    __syncthreads();

    // p5c: combine bases -> MFMA @ Wrel -> bf16 msg into out
    for (int g = wv; g < 21; g += 8) {
        int r = g / 3, mt = g - 3 * r;
        float c0, c1, c2;
        switch (r) {
            case 0: c0 = 1.f;  c1 = 0.f;  c2 = 0.f;  break;
            case 1: c0 = 0.f;  c1 = 1.f;  c2 = 0.f;  break;
            case 2: c0 = 0.f;  c1 = 0.f;  c2 = 1.f;  break;
            case 3: c0 = .5f;  c1 = .5f;  c2 = 0.f;  break;
            case 4: c0 = .5f;  c1 = 0.f;  c2 = .5f;  break;
            case 5: c0 = 0.f;  c1 = .5f;  c2 = .5f;  break;
            default: c0 = c1 = c2 = (1.f / 3.f);     break;
        }
        int row = mt * 16 + (ln & 15);
        float rvf = (row < N_) ? 1.f : 0.f;
        int rowc = (row < N_) ? row : 34;
        int k0 = (ln >> 4) << 3;
        const float* a0 = (const float*)(smem + AXB_OFF) + rowc * 44 + k0;
        const float* a1 = a0 + 35 * 44;
        const float* a2 = a1 + 35 * 44;
        f32x4 p0 = *(const f32x4*)a0,  p1 = *(const f32x4*)(a0 + 4);
        f32x4 u0 = *(const f32x4*)a1,  u1 = *(const f32x4*)(a1 + 4);
        f32x4 w0 = *(const f32x4*)a2,  w1 = *(const f32x4*)(a2 + 4);
        short8 aF;
#pragma unroll
        for (int i = 0; i < 4; ++i) {
            aF[i]     = (short)f2bf((c0 * p0[i] + c1 * u0[i] + c2 * w0[i]) * rvf);
            aF[i + 4] = (short)f2bf((c0 * p1[i] + c1 * u1[i] + c2 * w1[i]) * rvf);
        }
        unsigned short* outr = (unsigned short*)out
                             + (((size_t)t * R_ + r) * B_ + b) * ((size_t)N_ * 128);
#pragma unroll
        for (int nt = 0; nt < 4; ++nt) {
            short8 bb = *(const short8*)(WRELF + (r * 4 + nt) * 512 + ln * 8);
            f32x4 d = {0.f, 0.f, 0.f, 0.f};
            d = __builtin_amdgcn_mfma_f32_16x16x32_bf16(aF, bb, d, 0, 0, 0);
            int col = nt * 16 + (ln & 15);
#pragma unroll
            for (int j = 0; j < 4; ++j) {
                int rw = mt * 16 + ((ln >> 4) << 2) + j;
                if (rw < N_) outr[rw * 128 + 64 + col] = f2bf(fmaxf(d[j], 0.f));
            }
        }
    }
}

// ---- gate_kernel: 512 threads (8 waves), 2 blocks/CU; W6 in LDS + per-wave bounce ----
#define GATE_BOUNCE_STRIDE 66
#define GATE_LDS (49152 + 8 * 16 * GATE_BOUNCE_STRIDE * 2)   // 49152+16896 = 66048

__launch_bounds__(512, 4)
__global__ void gate_kernel(const float* __restrict__ h0,
                            const unsigned short* __restrict__ wsF,
                            const float* __restrict__ bz, const float* __restrict__ brg,
                            const float* __restrict__ bh,
                            float* out) {
    extern __shared__ char gsm[];
    unsigned short* W6L = (unsigned short*)gsm;
    const int tid = threadIdx.x;
    const int wv = tid >> 6, ln = tid & 63;
    const int blk = blockIdx.x;
    const int b = blk >> 1;
    const int tile = ((blk & 1) << 3) + wv;            // 16 tiles across 2 blocks
    unsigned short* tb = (unsigned short*)(gsm + 49152) + wv * (16 * GATE_BOUNCE_STRIDE);
    const size_t TS = (size_t)R_ * B_ * N_ * 64;       // floats per t-slab

    for (int e = tid; e < 3072; e += 512)
        ((short8*)W6L)[e] = ((const short8*)wsF)[e];
    __syncthreads();

    int ga = tile * 16 + (ln & 15); if (ga > 244) ga = 244;
    const size_t g_row = (size_t)((ga / 35) * B_ + b) * N_ + (ga % 35);
    const size_t moff = g_row * 128 + 64 + ((ln >> 4) << 3);        // bf16 msg (shorts)
    const int colb = ln & 15;
    int coff[4]; bool vj[4];
#pragma unroll
    for (int j = 0; j < 4; ++j) {
        int g = tile * 16 + ((ln >> 4) << 2) + j;
        vj[j] = (g < 245);
        int gc = vj[j] ? g : 244;
        coff[j] = (((gc / 35) * B_ + b) * N_ + (gc % 35)) * 64;
    }
    float bzv[4], brv[4], bhv[4];
#pragma unroll
    for (int nt = 0; nt < 4; ++nt) {
        int c = nt * 16 + colb;
        bzv[nt] = bz[c]; brv[nt] = brg[c]; bhv[nt] = bh[c];
    }

    short8 ah[2];
    float hp[4][4];
    {
        const float* hA = h0 + g_row * 64 + ((ln >> 4) << 3);
#pragma unroll
        for (int ks = 0; ks < 2; ++ks) {
            f32x4 u = *(const f32x4*)(hA + ks * 32);
            f32x4 v = *(const f32x4*)(hA + ks * 32 + 4);
            short8 s;
#pragma unroll
            for (int e = 0; e < 4; ++e) { s[e] = (short)f2bf(u[e]); s[e + 4] = (short)f2bf(v[e]); }
            ah[ks] = s;
        }
#pragma unroll
        for (int nt = 0; nt < 4; ++nt)
#pragma unroll
            for (int j = 0; j < 4; ++j) hp[nt][j] = h0[coff[j] + nt * 16 + colb];
    }
    // prefetch bf16 msg for t=0
    const unsigned short* outS = (const unsigned short*)out;
    short8 mpA = *(const short8*)(outS + moff);
    short8 mpB = *(const short8*)(outS + moff + 32);

    for (int t = 0; t < T_; ++t) {
        short8 amsg[2];
        amsg[0] = mpA; amsg[1] = mpB;
        {   // prefetch next t's msg (disjoint t-slab; clamped at end)
            int tn = (t < T_ - 1) ? (t + 1) : (T_ - 1);
            const unsigned short* mS = outS + (size_t)tn * (TS * 2) + moff;
            mpA = *(const short8*)(mS);
            mpB = *(const short8*)(mS + 32);
        }
        float zC[4][4];
#pragma unroll
        for (int nt = 0; nt < 4; ++nt) {
            // chain-split: msg-half and h-half accumulate independently (depth 2), then add
            f32x4 z  = {bzv[nt], bzv[nt], bzv[nt], bzv[nt]};
            f32x4 z2 = {0.f, 0.f, 0.f, 0.f};
            f32x4 rg = {brv[nt], brv[nt], brv[nt], brv[nt]};
            f32x4 rg2 = {0.f, 0.f, 0.f, 0.f};
            const unsigned short* wb = W6L + ln * 8 + nt * 1024;
            z   = __builtin_amdgcn_mfma_f32_16x16x32_bf16(amsg[0], *(const short8*)(wb),          z,   0, 0, 0);
            z2  = __builtin_amdgcn_mfma_f32_16x16x32_bf16(amsg[1], *(const short8*)(wb + 512),    z2,  0, 0, 0);
            z   = __builtin_amdgcn_mfma_f32_16x16x32_bf16(ah[0],   *(const short8*)(wb + 4096),   z,   0, 0, 0);
            z2  = __builtin_amdgcn_mfma_f32_16x16x32_bf16(ah[1],   *(const short8*)(wb + 4608),   z2,  0, 0, 0);
            rg  = __builtin_amdgcn_mfma_f32_16x16x32_bf16(amsg[0], *(const short8*)(wb + 8192),   rg,  0, 0, 0);
            rg2 = __builtin_amdgcn_mfma_f32_16x16x32_bf16(amsg[1], *(const short8*)(wb + 8704),   rg2, 0, 0, 0);
            rg  = __builtin_amdgcn_mfma_f32_16x16x32_bf16(ah[0],   *(const short8*)(wb + 12288),  rg,  0, 0, 0);
            rg2 = __builtin_amdgcn_mfma_f32_16x16x32_bf16(ah[1],   *(const short8*)(wb + 12800),  rg2, 0, 0, 0);
#pragma unroll
            for (int j = 0; j < 4; ++j) {
                float zv = __builtin_amdgcn_rcpf(1.f + __expf(-(z[j] + z2[j])));
                float rv = __builtin_amdgcn_rcpf(1.f + __expf(-(rg[j] + rg2[j])));
                zC[nt][j] = zv;
                tb[(((ln >> 4) << 2) + j) * GATE_BOUNCE_STRIDE + nt * 16 + colb] = f2bf(rv * hp[nt][j]);
            }
        }
        short8 arh[2];
#pragma unroll
        for (int ks = 0; ks < 2; ++ks)
            arh[ks] = *(const short8*)(tb + (ln & 15) * GATE_BOUNCE_STRIDE + ks * 32 + ((ln >> 4) << 3));
        float* outT = out + (size_t)t * TS;
#pragma unroll
        for (int nt = 0; nt < 4; ++nt) {
            f32x4 m  = {bhv[nt], bhv[nt], bhv[nt], bhv[nt]};
            f32x4 m2 = {0.f, 0.f, 0.f, 0.f};
            const unsigned short* wb = W6L + ln * 8 + nt * 1024;
            m  = __builtin_amdgcn_mfma_f32_16x16x32_bf16(amsg[0], *(const short8*)(wb + 16384), m,  0, 0, 0);
            m2 = __builtin_amdgcn_mfma_f32_16x16x32_bf16(amsg[1], *(const short8*)(wb + 16896), m2, 0, 0, 0);
            m  = __builtin_amdgcn_mfma_f32_16x16x32_bf16(arh[0],  *(const short8*)(wb + 20480), m,  0, 0, 0);
            m2 = __builtin_amdgcn_mfma_f32_16x16x32_bf16(arh[1],  *(const short8*)(wb + 20992), m2, 0, 0, 0);
#pragma unroll
            for (int j = 0; j < 4; ++j) {
                float e2 = __expf(2.f * (m[j] + m2[j]));
                float th = 1.f - 2.f * __builtin_amdgcn_rcpf(1.f + e2);
                float hn = hp[nt][j] + zC[nt][j] * (th - hp[nt][j]);
                hp[nt][j] = hn;
                if (vj[j]) outT[coff[j] + nt * 16 + colb] = hn;
                tb[(((ln >> 4) << 2) + j) * GATE_BOUNCE_STRIDE + nt * 16 + colb] = f2bf(hn);
            }
        }
#pragma unroll
        for (int ks = 0; ks < 2; ++ks)
            ah[ks] = *(const short8*)(tb + (ln & 15) * GATE_BOUNCE_STRIDE + ks * 32 + ((ln >> 4) << 3));
    }
}

extern "C" void kernel_launch(void* const* d_in, const int* in_sizes, int n_in,
                              void* d_out, int out_size, void* d_ws, size_t ws_size,
                              hipStream_t stream) {
    const float* x    = (const float*)d_in[0];
    const float* As   = (const float*)d_in[1];
    const float* Af   = (const float*)d_in[2];
    const float* At   = (const float*)d_in[3];
    const float* h0   = (const float*)d_in[4];
    const float* Wq   = (const float*)d_in[5];
    const float* Wk   = (const float*)d_in[6];
    const float* V    = (const float*)d_in[7];
    const float* coef = (const float*)d_in[8];
    const float* Uz   = (const float*)d_in[9];
    const float* Wz   = (const float*)d_in[10];
    const float* bz   = (const float*)d_in[11];
    const float* Ur   = (const float*)d_in[12];
    const float* Wrg  = (const float*)d_in[13];
    const float* brg  = (const float*)d_in[14];
    const float* Uh   = (const float*)d_in[15];
    const float* Wh   = (const float*)d_in[16];
    const float* bh   = (const float*)d_in[17];
    float* out = (float*)d_out;
    unsigned short* wsF = (unsigned short*)d_ws;  // 86016 B used

    hipFuncSetAttribute((const void*)gate_kernel,
                        hipFuncAttributeMaxDynamicSharedMemorySize, GATE_LDS);

    hipLaunchKernelGGL(pack_kernel, dim3(168), dim3(256), 0, stream,
                       Wq, Wk, coef, V, Uz, Wz, Ur, Wrg, Uh, Wh, wsF);
    hipLaunchKernelGGL(msg_kernel, dim3(T_ * B_), dim3(512), 0, stream,
                       x, As, Af, At, wsF, out);
    hipLaunchKernelGGL(gate_kernel, dim3(B_ * 2), dim3(512), GATE_LDS, stream,
                       h0, wsF, bz, brg, bh, out);
}

// Round 14
// 160.479 us; speedup vs baseline: 1.1704x; 1.1704x over previous
//
#include <hip/hip_runtime.h>

typedef short short8 __attribute__((ext_vector_type(8)));
typedef float f32x4 __attribute__((ext_vector_type(4)));

#define T_ 12
#define B_ 256
#define N_ 35
#define M_ 29
#define H_ 64
#define R_ 7

// ---- ws (shorts) layout: packed bf16 MFMA B-fragments ----
// W6F   @0     : 6 mats x [nt4][ks2][64][8]   = 24576 shorts
// WQKF  @24576 : 2 mats x [nt4][64][8]        = 4096
// WRELF @28672 : 7 r    x [nt4][64][8]        = 14336

// ---- msg_kernel static LDS (bytes), phase-overlaid ----
#define XA_OFF   0
#define XB_OFF   3072
#define Q_OFF    7168
#define K_OFF    16384
#define E_OFF    25344
#define INV_OFF  46064
#define S2_OFF   7168
#define AN_OFF   12208
#define AXB_OFF  20608
#define SMEM_A   47232

__device__ __forceinline__ unsigned short f2bf(float f) {
    unsigned int u = __float_as_uint(f);
    u += 0x7fffu + ((u >> 16) & 1u);
    return (unsigned short)(u >> 16);
}
__device__ __forceinline__ float bf2f(unsigned short s) {
    return __uint_as_float(((unsigned int)s) << 16);
}

// ---------------- pack: weights -> bf16 fragment order in ws ----------------
__global__ void pack_kernel(const float* __restrict__ Wq, const float* __restrict__ Wk,
                            const float* __restrict__ coef, const float* __restrict__ V,
                            const float* __restrict__ Uz, const float* __restrict__ Wz,
                            const float* __restrict__ Ur, const float* __restrict__ Wrg,
                            const float* __restrict__ Uh, const float* __restrict__ Wh,
                            unsigned short* __restrict__ ws) {
    int idx = blockIdx.x * 256 + threadIdx.x;   // grid covers exactly 43008
    if (idx < 24576) {                          // W6
        int mat = idx >> 12, rem = idx & 4095;
        int i = rem & 7, l = (rem >> 3) & 63, ks = (rem >> 9) & 1, nt = rem >> 10;
        int j = ks * 32 + ((l >> 4) << 3) + i, c = nt * 16 + (l & 15);
        const float* W = (mat == 0) ? Uz : (mat == 1) ? Wz : (mat == 2) ? Ur
                       : (mat == 3) ? Wrg : (mat == 4) ? Uh : Wh;
        ws[idx] = f2bf(W[j * 64 + c]);
    } else if (idx < 28672) {                   // WQK
        int rem = idx - 24576;
        int mq = rem >> 11; rem &= 2047;
        int i = rem & 7, l = (rem >> 3) & 63, nt = rem >> 9;
        int j = ((l >> 4) << 3) + i, c = nt * 16 + (l & 15);
        const float* W = mq ? Wk : Wq;
        ws[idx] = (j < M_) ? f2bf(W[j * 64 + c]) : (unsigned short)0;
    } else {                                    // WREL
        int rem = idx - 28672;
        int r = rem >> 11; rem &= 2047;
        int i = rem & 7, l = (rem >> 3) & 63, nt = rem >> 9;
        int j = ((l >> 4) << 3) + i, c = nt * 16 + (l & 15);
        unsigned short v = 0;
        if (j < M_) {
            float a = 0.f;
#pragma unroll
            for (int bb = 0; bb < 3; ++bb) a += coef[r * 3 + bb] * V[(bb * M_ + j) * 64 + c];
            v = f2bf(a);
        }
        ws[idx] = v;
    }
}

// --------- msg: one block per (t,b); msg bf16 -> upper half of out[t] rows ---------
__launch_bounds__(512, 4)
__global__ void msg_kernel(const float* __restrict__ x,
                           const float* __restrict__ As, const float* __restrict__ Af,
                           const float* __restrict__ At,
                           const unsigned short* __restrict__ wsF,
                           float* __restrict__ out) {
    __shared__ __align__(16) char smem[SMEM_A];
    const int blk = blockIdx.x;
    const int t = blk >> 8, b = blk & 255;
    const int tid = threadIdx.x, wv = tid >> 6, ln = tid & 63;
    const unsigned short* WQKF  = wsF + 24576;
    const unsigned short* WRELF = wsF + 28672;
    const float* __restrict__ xt = x + ((size_t)t * B_ + b) * (N_ * M_);

    for (int e = tid; e < 1536; e += 512) {
        int mt = e >> 9, l = (e >> 3) & 63, i = e & 7;
        int row = mt * 16 + (l & 15), k = ((l >> 4) << 3) + i;
        float v = (row < N_ && k < M_) ? xt[row * M_ + k] : 0.f;
        *(unsigned short*)(smem + XA_OFF + e * 2) = f2bf(v);
    }
    for (int e = tid; e < 2048; e += 512) {
        int g = e >> 9, l = (e >> 3) & 63, i = e & 7;
        int ks = g >> 1, nt = g & 1;
        int k = ks * 32 + ((l >> 4) << 3) + i, c = nt * 16 + (l & 15);
        float v = (k < N_ && c < M_) ? xt[k * M_ + c] : 0.f;
        *(unsigned short*)(smem + XB_OFF + e * 2) = f2bf(v);
    }
    __syncthreads();

    // p2: q = x@Wq (swz fp32), k = x@Wk (linear fp32)
    for (int tile = wv; tile < 24; tile += 8) {
        int qk = (tile >= 12) ? 1 : 0;
        int tt = tile - 12 * qk;
        int mt = tt >> 2, nt = tt & 3;
        short8 a  = *(const short8*)(smem + XA_OFF + (mt * 64 + ln) * 16);
        short8 bb = *(const short8*)(WQKF + (qk * 4 + nt) * 512 + ln * 8);
        f32x4 d = {0.f, 0.f, 0.f, 0.f};
        d = __builtin_amdgcn_mfma_f32_16x16x32_bf16(a, bb, d, 0, 0, 0);
        int col = nt * 16 + (ln & 15);
#pragma unroll
        for (int j = 0; j < 4; ++j) {
            int row = mt * 16 + ((ln >> 4) << 2) + j;
            if (row < N_) {
                if (qk) *(float*)(smem + K_OFF + (row * 64 + col) * 4) = d[j];
                else {
                    int ad = (Q_OFF + row * 256 + col * 4) ^ ((row & 7) << 4);
                    *(float*)(smem + ad) = d[j];
                }
            }
        }
    }
    __syncthreads();

    // p3: wave = head; lane = n-row; single-pass exp (no max, no atomics)
    {
        const int hd = wv, n = ln;
        const int nn = (n < N_) ? n : 34;
        const int qb = Q_OFF + nn * 256 + hd * 32;
        const int swzq = (nn & 7) << 4;
        f32x4 q0 = *(const f32x4*)(smem + (qb ^ swzq));
        f32x4 q1 = *(const f32x4*)(smem + ((qb + 16) ^ swzq));
        float sum = 0.f;
        unsigned short* Erow = (unsigned short*)(smem + E_OFF) + (hd * 35 + nn) * 37;
#pragma unroll
        for (int m = 0; m < N_; ++m) {
            f32x4 k0 = *(const f32x4*)(smem + K_OFF + (m * 64 + hd * 8) * 4);
            f32x4 k1 = *(const f32x4*)(smem + K_OFF + (m * 64 + hd * 8 + 4) * 4);
            float acc = q0[0]*k0[0] + q0[1]*k0[1] + q0[2]*k0[2] + q0[3]*k0[3]
                      + q1[0]*k1[0] + q1[1]*k1[1] + q1[2]*k1[2] + q1[3]*k1[3];
            float e = __expf(acc * 0.3535533905932738f);
            sum += e;
            if (n < N_) Erow[m] = f2bf(e);
        }
        if (n < N_) *((float*)(smem + INV_OFF) + hd * 35 + n) = 1.f / sum;
    }
    __syncthreads();

    // p3.5: S[n][m] = sum_h E*inv
    {
        const unsigned short* E = (const unsigned short*)(smem + E_OFF);
        const float* IV = (const float*)(smem + INV_OFF);
        float* S = (float*)(smem + S2_OFF);
        for (int e = tid; e < 1225; e += 512) {
            int n = e / 35, m = e - n * 35;
            float s = 0.f;
#pragma unroll
            for (int h = 0; h < 8; ++h)
                s += bf2f(E[(h * 35 + n) * 37 + m]) * IV[h * 35 + n];
            S[n * 36 + m] = s;
        }
    }
    __syncthreads();

    // p4: An = l2norm(A * S)
    if (tid < 420) {
        int g = tid >> 2, sub = tid & 3;
        int mat = g / N_, j = g - N_ * mat;
        const float* __restrict__ A = (mat == 0) ? As : ((mat == 1) ? Af : At);
        float vals[9]; float ss = 0.f;
#pragma unroll
        for (int i = 0; i < 9; ++i) {
            int n = sub + 4 * i;
            float vv = 0.f;
            if (n < N_) vv = A[n * N_ + j] * *((const float*)(smem + S2_OFF) + n * 36 + j);
            vals[i] = vv; ss += vv * vv;
        }
        ss += __shfl_xor(ss, 1);
        ss += __shfl_xor(ss, 2);
        float inv = 1.f / fmaxf(sqrtf(ss), 1e-12f);
#pragma unroll
        for (int i = 0; i < 9; ++i) {
            int n = sub + 4 * i;
            if (n < N_)
                *(unsigned short*)(smem + AN_OFF + ((mat * 35 + n) * 40 + j) * 2) = f2bf(vals[i] * inv);
        }
    }
    for (int e = tid; e < 525; e += 512) {
        int mat = e / 175, rem = e - mat * 175;
        int n = rem / 5, pc = rem - n * 5;
        *(unsigned short*)(smem + AN_OFF + ((mat * 35 + n) * 40 + 35 + pc) * 2) = 0;
    }
    __syncthreads();

    // p5a: 3 base products An_i @ x
    for (int g = wv; g < 9; g += 8) {
        int base = g / 3, mt = g - 3 * base;
        const int row = mt * 16 + (ln & 15);
        const int rowc = (row < N_) ? row : 34;
        const short8 z8 = {0, 0, 0, 0, 0, 0, 0, 0};
        short8 aF[2];
#pragma unroll
        for (int ks = 0; ks < 2; ++ks) {
            int k0 = ks * 32 + ((ln >> 4) << 3);
            int k0c = (k0 <= 32) ? k0 : 32;
            short8 v = *(const short8*)(smem + AN_OFF + ((base * 35 + rowc) * 40 + k0c) * 2);
            aF[ks] = (row < N_ && k0 <= 32) ? v : z8;
        }
        float* axb = (float*)(smem + AXB_OFF) + base * (35 * 44);
#pragma unroll
        for (int nt = 0; nt < 2; ++nt) {
            f32x4 d = {0.f, 0.f, 0.f, 0.f};
#pragma unroll
            for (int ks = 0; ks < 2; ++ks) {
                short8 bb = *(const short8*)(smem + XB_OFF + ((ks * 2 + nt) * 64 + ln) * 16);
                d = __builtin_amdgcn_mfma_f32_16x16x32_bf16(aF[ks], bb, d, 0, 0, 0);
            }
            int col = nt * 16 + (ln & 15);
#pragma unroll
            for (int j = 0; j < 4; ++j) {
                int rw = mt * 16 + ((ln >> 4) << 2) + j;
                if (rw < N_) axb[rw * 44 + col] = d[j];
            }
        }
    }
    __syncthreads();

    // p5c: combine bases -> MFMA @ Wrel -> bf16 msg into out
    for (int g = wv; g < 21; g += 8) {
        int r = g / 3, mt = g - 3 * r;
        float c0, c1, c2;
        switch (r) {
            case 0: c0 = 1.f;  c1 = 0.f;  c2 = 0.f;  break;
            case 1: c0 = 0.f;  c1 = 1.f;  c2 = 0.f;  break;
            case 2: c0 = 0.f;  c1 = 0.f;  c2 = 1.f;  break;
            case 3: c0 = .5f;  c1 = .5f;  c2 = 0.f;  break;
            case 4: c0 = .5f;  c1 = 0.f;  c2 = .5f;  break;
            case 5: c0 = 0.f;  c1 = .5f;  c2 = .5f;  break;
            default: c0 = c1 = c2 = (1.f / 3.f);     break;
        }
        int row = mt * 16 + (ln & 15);
        float rvf = (row < N_) ? 1.f : 0.f;
        int rowc = (row < N_) ? row : 34;
        int k0 = (ln >> 4) << 3;
        const float* a0 = (const float*)(smem + AXB_OFF) + rowc * 44 + k0;
        const float* a1 = a0 + 35 * 44;
        const float* a2 = a1 + 35 * 44;
        f32x4 p0 = *(const f32x4*)a0,  p1 = *(const f32x4*)(a0 + 4);
        f32x4 u0 = *(const f32x4*)a1,  u1 = *(const f32x4*)(a1 + 4);
        f32x4 w0 = *(const f32x4*)a2,  w1 = *(const f32x4*)(a2 + 4);
        short8 aF;
#pragma unroll
        for (int i = 0; i < 4; ++i) {
            aF[i]     = (short)f2bf((c0 * p0[i] + c1 * u0[i] + c2 * w0[i]) * rvf);
            aF[i + 4] = (short)f2bf((c0 * p1[i] + c1 * u1[i] + c2 * w1[i]) * rvf);
        }
        unsigned short* outr = (unsigned short*)out
                             + (((size_t)t * R_ + r) * B_ + b) * ((size_t)N_ * 128);
#pragma unroll
        for (int nt = 0; nt < 4; ++nt) {
            short8 bb = *(const short8*)(WRELF + (r * 4 + nt) * 512 + ln * 8);
            f32x4 d = {0.f, 0.f, 0.f, 0.f};
            d = __builtin_amdgcn_mfma_f32_16x16x32_bf16(aF, bb, d, 0, 0, 0);
            int col = nt * 16 + (ln & 15);
#pragma unroll
            for (int j = 0; j < 4; ++j) {
                int rw = mt * 16 + ((ln >> 4) << 2) + j;
                if (rw < N_) outr[rw * 128 + 64 + col] = f2bf(fmaxf(d[j], 0.f));
            }
        }
    }
}

// ---- gate_kernel: 512 threads (8 waves), 2 blocks/CU; W6 in LDS + per-wave bounce ----
#define GATE_BOUNCE_STRIDE 66
#define GATE_LDS (49152 + 8 * 16 * GATE_BOUNCE_STRIDE * 2)   // 49152+16896 = 66048

__launch_bounds__(512, 4)
__global__ void gate_kernel(const float* __restrict__ h0,
                            const unsigned short* __restrict__ wsF,
                            const float* __restrict__ bz, const float* __restrict__ brg,
                            const float* __restrict__ bh,
                            float* out) {
    extern __shared__ char gsm[];
    unsigned short* W6L = (unsigned short*)gsm;
    const int tid = threadIdx.x;
    const int wv = tid >> 6, ln = tid & 63;
    const int blk = blockIdx.x;
    const int b = blk >> 1;
    const int tile = ((blk & 1) << 3) + wv;            // 16 tiles across 2 blocks
    unsigned short* tb = (unsigned short*)(gsm + 49152) + wv * (16 * GATE_BOUNCE_STRIDE);
    const size_t TS = (size_t)R_ * B_ * N_ * 64;       // floats per t-slab

    for (int e = tid; e < 3072; e += 512)
        ((short8*)W6L)[e] = ((const short8*)wsF)[e];
    __syncthreads();

    int ga = tile * 16 + (ln & 15); if (ga > 244) ga = 244;
    const size_t g_row = (size_t)((ga / 35) * B_ + b) * N_ + (ga % 35);
    const size_t moff = g_row * 128 + 64 + ((ln >> 4) << 3);        // bf16 msg (shorts)
    const int colb = ln & 15;
    int coff[4]; bool vj[4];
#pragma unroll
    for (int j = 0; j < 4; ++j) {
        int g = tile * 16 + ((ln >> 4) << 2) + j;
        vj[j] = (g < 245);
        int gc = vj[j] ? g : 244;
        coff[j] = (((gc / 35) * B_ + b) * N_ + (gc % 35)) * 64;
    }
    float bzv[4], brv[4], bhv[4];
#pragma unroll
    for (int nt = 0; nt < 4; ++nt) {
        int c = nt * 16 + colb;
        bzv[nt] = bz[c]; brv[nt] = brg[c]; bhv[nt] = bh[c];
    }

    short8 ah[2];
    float hp[4][4];
    {
        const float* hA = h0 + g_row * 64 + ((ln >> 4) << 3);
#pragma unroll
        for (int ks = 0; ks < 2; ++ks) {
            f32x4 u = *(const f32x4*)(hA + ks * 32);
            f32x4 v = *(const f32x4*)(hA + ks * 32 + 4);
            short8 s;
#pragma unroll
            for (int e = 0; e < 4; ++e) { s[e] = (short)f2bf(u[e]); s[e + 4] = (short)f2bf(v[e]); }
            ah[ks] = s;
        }
#pragma unroll
        for (int nt = 0; nt < 4; ++nt)
#pragma unroll
            for (int j = 0; j < 4; ++j) hp[nt][j] = h0[coff[j] + nt * 16 + colb];
    }
    // prefetch bf16 msg for t=0
    const unsigned short* outS = (const unsigned short*)out;
    short8 mpA = *(const short8*)(outS + moff);
    short8 mpB = *(const short8*)(outS + moff + 32);

    for (int t = 0; t < T_; ++t) {
        short8 amsg[2];
        amsg[0] = mpA; amsg[1] = mpB;
        {   // prefetch next t's msg (disjoint t-slab; clamped at end)
            int tn = (t < T_ - 1) ? (t + 1) : (T_ - 1);
            const unsigned short* mS = outS + (size_t)tn * (TS * 2) + moff;
            mpA = *(const short8*)(mS);
            mpB = *(const short8*)(mS + 32);
        }
        float zC[4][4];
#pragma unroll
        for (int nt = 0; nt < 4; ++nt) {
            f32x4 z  = {bzv[nt], bzv[nt], bzv[nt], bzv[nt]};
            f32x4 rg = {brv[nt], brv[nt], brv[nt], brv[nt]};
#pragma unroll
            for (int ks = 0; ks < 2; ++ks) {
                const unsigned short* wb = W6L + ln * 8 + nt * 1024 + ks * 512;
                z  = __builtin_amdgcn_mfma_f32_16x16x32_bf16(amsg[ks], *(const short8*)(wb),         z, 0, 0, 0);
                z  = __builtin_amdgcn_mfma_f32_16x16x32_bf16(ah[ks],   *(const short8*)(wb + 4096),  z, 0, 0, 0);
                rg = __builtin_amdgcn_mfma_f32_16x16x32_bf16(amsg[ks], *(const short8*)(wb + 8192),  rg, 0, 0, 0);
                rg = __builtin_amdgcn_mfma_f32_16x16x32_bf16(ah[ks],   *(const short8*)(wb + 12288), rg, 0, 0, 0);
            }
#pragma unroll
            for (int j = 0; j < 4; ++j) {
                float zv = __builtin_amdgcn_rcpf(1.f + __expf(-z[j]));
                float rv = __builtin_amdgcn_rcpf(1.f + __expf(-rg[j]));
                zC[nt][j] = zv;
                tb[(((ln >> 4) << 2) + j) * GATE_BOUNCE_STRIDE + nt * 16 + colb] = f2bf(rv * hp[nt][j]);
            }
        }
        short8 arh[2];
#pragma unroll
        for (int ks = 0; ks < 2; ++ks)
            arh[ks] = *(const short8*)(tb + (ln & 15) * GATE_BOUNCE_STRIDE + ks * 32 + ((ln >> 4) << 3));
        float* outT = out + (size_t)t * TS;
#pragma unroll
        for (int nt = 0; nt < 4; ++nt) {
            f32x4 m = {bhv[nt], bhv[nt], bhv[nt], bhv[nt]};
#pragma unroll
            for (int ks = 0; ks < 2; ++ks) {
                const unsigned short* wb = W6L + ln * 8 + nt * 1024 + ks * 512;
                m = __builtin_amdgcn_mfma_f32_16x16x32_bf16(amsg[ks], *(const short8*)(wb + 16384), m, 0, 0, 0);
                m = __builtin_amdgcn_mfma_f32_16x16x32_bf16(arh[ks],  *(const short8*)(wb + 20480), m, 0, 0, 0);
            }
#pragma unroll
            for (int j = 0; j < 4; ++j) {
                float e2 = __expf(2.f * m[j]);
                float th = 1.f - 2.f * __builtin_amdgcn_rcpf(1.f + e2);
                float hn = hp[nt][j] + zC[nt][j] * (th - hp[nt][j]);
                hp[nt][j] = hn;
                if (vj[j]) outT[coff[j] + nt * 16 + colb] = hn;
                tb[(((ln >> 4) << 2) + j) * GATE_BOUNCE_STRIDE + nt * 16 + colb] = f2bf(hn);
            }
        }
#pragma unroll
        for (int ks = 0; ks < 2; ++ks)
            ah[ks] = *(const short8*)(tb + (ln & 15) * GATE_BOUNCE_STRIDE + ks * 32 + ((ln >> 4) << 3));
    }
}

extern "C" void kernel_launch(void* const* d_in, const int* in_sizes, int n_in,
                              void* d_out, int out_size, void* d_ws, size_t ws_size,
                              hipStream_t stream) {
    const float* x    = (const float*)d_in[0];
    const float* As   = (const float*)d_in[1];
    const float* Af   = (const float*)d_in[2];
    const float* At   = (const float*)d_in[3];
    const float* h0   = (const float*)d_in[4];
    const float* Wq   = (const float*)d_in[5];
    const float* Wk   = (const float*)d_in[6];
    const float* V    = (const float*)d_in[7];
    const float* coef = (const float*)d_in[8];
    const float* Uz   = (const float*)d_in[9];
    const float* Wz   = (const float*)d_in[10];
    const float* bz   = (const float*)d_in[11];
    const float* Ur   = (const float*)d_in[12];
    const float* Wrg  = (const float*)d_in[13];
    const float* brg  = (const float*)d_in[14];
    const float* Uh   = (const float*)d_in[15];
    const float* Wh   = (const float*)d_in[16];
    const float* bh   = (const float*)d_in[17];
    float* out = (float*)d_out;
    unsigned short* wsF = (unsigned short*)d_ws;  // 86016 B used

    hipFuncSetAttribute((const void*)gate_kernel,
                        hipFuncAttributeMaxDynamicSharedMemorySize, GATE_LDS);

    hipLaunchKernelGGL(pack_kernel, dim3(168), dim3(256), 0, stream,
                       Wq, Wk, coef, V, Uz, Wz, Ur, Wrg, Uh, Wh, wsF);
    hipLaunchKernelGGL(msg_kernel, dim3(T_ * B_), dim3(512), 0, stream,
                       x, As, Af, At, wsF, out);
    hipLaunchKernelGGL(gate_kernel, dim3(B_ * 2), dim3(512), GATE_LDS, stream,
                       h0, wsF, bz, brg, bh, out);
}